// Round 2
// baseline (1081.874 us; speedup 1.0000x reference)
//
#include <hip/hip_runtime.h>
#include <hip/hip_bf16.h>

#define D_MODEL 1024
#define NHEADS 16
#define HDIM 64
#define BATCH 8
#define SEQ 512
#define NROWS 4096          // BATCH*SEQ
#define SCALE 0.125f
#define LN_EPS 1e-5f

static __device__ __forceinline__ float bf2f(unsigned short u) {
    return __uint_as_float(((unsigned int)u) << 16);
}
static __device__ __forceinline__ unsigned short f2bf(float f) {
    unsigned int x = __float_as_uint(f);
    unsigned int r = (x + 0x7fffu + ((x >> 16) & 1u)) >> 16;   // RNE
    return (unsigned short)r;
}

// ---------------------------------------------------------------------------
// Bias: jax.image.resize(bias128, (512,512), 'bilinear')
// half-pixel centers: f = (o+0.5)/4 - 0.5 ; edge weights normalize to clamping
// ---------------------------------------------------------------------------
static __device__ __forceinline__ float bias128(int a, int b) {
    float d = fabsf((float)(a - b));
    return expf(-d * 0.1f) - d * 0.05f;
}

__global__ void bias_kernel(float* __restrict__ bias) {
    int idx = blockIdx.x * 256 + threadIdx.x;
    if (idx >= 512 * 512) return;
    int qi = idx >> 9, kj = idx & 511;
    float fq = (qi + 0.5f) * 0.25f - 0.5f;
    float fk = (kj + 0.5f) * 0.25f - 0.5f;
    int iq = (int)floorf(fq); float tq = fq - (float)iq;
    int ik = (int)floorf(fk); float tk = fk - (float)ik;
    int iq0 = min(max(iq, 0), 127), iq1 = min(max(iq + 1, 0), 127);
    int ik0 = min(max(ik, 0), 127), ik1 = min(max(ik + 1, 0), 127);
    float v = (1.f - tq) * ((1.f - tk) * bias128(iq0, ik0) + tk * bias128(iq0, ik1))
            +        tq  * ((1.f - tk) * bias128(iq1, ik0) + tk * bias128(iq1, ik1));
    bias[idx] = v;
}

// ---------------------------------------------------------------------------
// LayerNorm of both streams -> bf16
// ---------------------------------------------------------------------------
__global__ void ln_kernel(const float* __restrict__ dec, const float* __restrict__ enc,
                          const float* __restrict__ gamma, const float* __restrict__ beta,
                          unsigned short* __restrict__ q_ln, unsigned short* __restrict__ kv_ln) {
    int row = blockIdx.x;                       // 0..8191
    const float* src = (row < NROWS) ? dec + (size_t)row * D_MODEL
                                     : enc + (size_t)(row - NROWS) * D_MODEL;
    unsigned short* dst = (row < NROWS) ? q_ln + (size_t)row * D_MODEL
                                        : kv_ln + (size_t)(row - NROWS) * D_MODEL;
    int t = threadIdx.x;
    float4 x = ((const float4*)src)[t];
    float s  = x.x + x.y + x.z + x.w;
    float ss = x.x * x.x + x.y * x.y + x.z * x.z + x.w * x.w;
    #pragma unroll
    for (int off = 32; off > 0; off >>= 1) {
        s  += __shfl_down(s, off);
        ss += __shfl_down(ss, off);
    }
    __shared__ float red_s[4], red_ss[4];
    int wid = t >> 6, lane = t & 63;
    if (lane == 0) { red_s[wid] = s; red_ss[wid] = ss; }
    __syncthreads();
    if (t == 0) {
        float S = red_s[0] + red_s[1] + red_s[2] + red_s[3];
        float SS = red_ss[0] + red_ss[1] + red_ss[2] + red_ss[3];
        red_s[0] = S; red_ss[0] = SS;
    }
    __syncthreads();
    float mu  = red_s[0] * (1.0f / 1024.0f);
    float var = red_ss[0] * (1.0f / 1024.0f) - mu * mu;
    float rstd = rsqrtf(var + LN_EPS);
    float4 g = ((const float4*)gamma)[t];
    float4 bb = ((const float4*)beta)[t];
    ushort4 u;
    u.x = f2bf((x.x - mu) * rstd * g.x + bb.x);
    u.y = f2bf((x.y - mu) * rstd * g.y + bb.y);
    u.z = f2bf((x.z - mu) * rstd * g.z + bb.z);
    u.w = f2bf((x.w - mu) * rstd * g.w + bb.w);
    ((ushort4*)dst)[t] = u;
}

// ---------------------------------------------------------------------------
// QKV GEMM (fp32 VALU): out(4096 x 3072) = LN_in @ Wqkv^T, fused RoPE,
// write q/k/v as (B,H,L,64) bf16.  Block tile 64x64, 256 thr, 4x4/thread.
// ---------------------------------------------------------------------------
__global__ void qkv_gemm(const unsigned short* __restrict__ q_ln,
                         const unsigned short* __restrict__ kv_ln,
                         const float* __restrict__ Wqkv,
                         unsigned short* __restrict__ qo,
                         unsigned short* __restrict__ ko,
                         unsigned short* __restrict__ vo) {
    int ct = blockIdx.x;            // 0..47
    int rt = blockIdx.y;            // 0..63
    int jbase = ct * 64;
    int section = jbase >> 10;      // 0=q 1=k 2=v
    int h = (jbase & 1023) >> 6;
    const unsigned short* A = (section == 0) ? q_ln : kv_ln;

    __shared__ float As[16][68];
    __shared__ float Bs[16][68];
    __shared__ float Cs[64][65];

    int tid = threadIdx.x;
    int tx = tid & 15, ty = tid >> 4;
    int arow = tid >> 2;            // 0..63
    int akk = (tid & 3) * 4;        // 0,4,8,12
    const unsigned short* Arow = A + (size_t)(rt * 64 + arow) * 1024;
    const float* Brow = Wqkv + (size_t)(jbase + arow) * 1024;

    float acc[4][4] = {};
    for (int kt = 0; kt < 64; ++kt) {
        int k0 = kt * 16;
        ushort4 av = *(const ushort4*)(Arow + k0 + akk);
        float4 bv = *(const float4*)(Brow + k0 + akk);
        As[akk + 0][arow] = bf2f(av.x);
        As[akk + 1][arow] = bf2f(av.y);
        As[akk + 2][arow] = bf2f(av.z);
        As[akk + 3][arow] = bf2f(av.w);
        Bs[akk + 0][arow] = bv.x;
        Bs[akk + 1][arow] = bv.y;
        Bs[akk + 2][arow] = bv.z;
        Bs[akk + 3][arow] = bv.w;
        __syncthreads();
        #pragma unroll
        for (int kk = 0; kk < 16; ++kk) {
            float4 a = *(const float4*)&As[kk][ty * 4];
            float4 b = *(const float4*)&Bs[kk][tx * 4];
            acc[0][0] += a.x * b.x; acc[0][1] += a.x * b.y; acc[0][2] += a.x * b.z; acc[0][3] += a.x * b.w;
            acc[1][0] += a.y * b.x; acc[1][1] += a.y * b.y; acc[1][2] += a.y * b.z; acc[1][3] += a.y * b.w;
            acc[2][0] += a.z * b.x; acc[2][1] += a.z * b.y; acc[2][2] += a.z * b.z; acc[2][3] += a.z * b.w;
            acc[3][0] += a.w * b.x; acc[3][1] += a.w * b.y; acc[3][2] += a.w * b.z; acc[3][3] += a.w * b.w;
        }
        __syncthreads();
    }
    #pragma unroll
    for (int i = 0; i < 4; ++i)
        #pragma unroll
        for (int j = 0; j < 4; ++j)
            Cs[ty * 4 + i][tx * 4 + j] = acc[i][j];
    __syncthreads();

    int r = tid >> 2;
    int d0 = (tid & 3) * 16;
    int grow = rt * 64 + r;
    int b = grow >> 9, l = grow & 511;
    unsigned short* outp = (section == 0) ? qo : (section == 1) ? ko : vo;
    size_t obase = (((size_t)b * NHEADS + h) * SEQ + l) * HDIM;

    if (section == 2) {
        #pragma unroll
        for (int j = 0; j < 16; ++j)
            outp[obase + d0 + j] = f2bf(Cs[r][d0 + j]);
    } else {
        #pragma unroll
        for (int j = 0; j < 16; ++j) {
            int d = d0 + j;
            int f = (d < 32) ? d : d - 32;
            float inv = expf(-0.2878231366f * (float)f);   // 10000^(-f/32)
            float ang = (float)l * inv;
            float c = cosf(ang), s = sinf(ang);
            float val = (d < 32) ? (Cs[r][d] * c - Cs[r][d + 32] * s)
                                 : (Cs[r][d - 32] * s + Cs[r][d] * c);
            outp[obase + d] = f2bf(val);
        }
    }
}

// ---------------------------------------------------------------------------
// Flash attention (fp32 VALU). One block per (b, h, 64-row q tile).
// ---------------------------------------------------------------------------
__global__ void attn_kernel(const unsigned short* __restrict__ q,
                            const unsigned short* __restrict__ k,
                            const unsigned short* __restrict__ v,
                            const float* __restrict__ bias,
                            unsigned short* __restrict__ attended) {
    int qt = blockIdx.x, h = blockIdx.y, b = blockIdx.z;
    __shared__ float Qs[64][65];
    __shared__ float Ks[64][65];
    __shared__ float Vs[64][65];
    __shared__ float Ps[64][65];
    int tid = threadIdx.x;
    int r = tid >> 2, cg = tid & 3, c0 = cg * 16;
    size_t headbase = (((size_t)b * NHEADS + h) * SEQ) * HDIM;
    int q0 = qt * 64;

    {
        const unsigned short* src = q + headbase + (size_t)(q0 + r) * HDIM + c0;
        #pragma unroll
        for (int j = 0; j < 16; j += 4) {
            ushort4 u = *(const ushort4*)(src + j);
            Qs[r][c0 + j + 0] = bf2f(u.x);
            Qs[r][c0 + j + 1] = bf2f(u.y);
            Qs[r][c0 + j + 2] = bf2f(u.z);
            Qs[r][c0 + j + 3] = bf2f(u.w);
        }
    }

    float oacc[16];
    #pragma unroll
    for (int i = 0; i < 16; ++i) oacc[i] = 0.f;
    float m = -1e30f, lsum = 0.f;

    for (int kt = 0; kt < 8; ++kt) {
        int kv0 = kt * 64;
        __syncthreads();    // previous PV done (and Qs visible on kt==0)
        {
            const unsigned short* ks = k + headbase + (size_t)(kv0 + r) * HDIM + c0;
            const unsigned short* vs = v + headbase + (size_t)(kv0 + r) * HDIM + c0;
            #pragma unroll
            for (int j = 0; j < 16; j += 4) {
                ushort4 uk = *(const ushort4*)(ks + j);
                ushort4 uv = *(const ushort4*)(vs + j);
                Ks[r][c0 + j + 0] = bf2f(uk.x); Ks[r][c0 + j + 1] = bf2f(uk.y);
                Ks[r][c0 + j + 2] = bf2f(uk.z); Ks[r][c0 + j + 3] = bf2f(uk.w);
                Vs[r][c0 + j + 0] = bf2f(uv.x); Vs[r][c0 + j + 1] = bf2f(uv.y);
                Vs[r][c0 + j + 2] = bf2f(uv.z); Vs[r][c0 + j + 3] = bf2f(uv.w);
            }
        }
        __syncthreads();

        float s[16];
        #pragma unroll
        for (int j = 0; j < 16; ++j) s[j] = 0.f;
        for (int d = 0; d < 64; ++d) {
            float qv = Qs[r][d];
            #pragma unroll
            for (int j = 0; j < 16; ++j) s[j] += qv * Ks[c0 + j][d];
        }

        const float* brow = bias + (size_t)(q0 + r) * 512 + kv0 + c0;
        float tmax = -1e30f;
        #pragma unroll
        for (int j = 0; j < 16; ++j) {
            s[j] = s[j] * SCALE + brow[j];
            tmax = fmaxf(tmax, s[j]);
        }
        tmax = fmaxf(tmax, __shfl_xor(tmax, 1));
        tmax = fmaxf(tmax, __shfl_xor(tmax, 2));
        float mnew = fmaxf(m, tmax);
        float alpha = expf(m - mnew);
        float ts = 0.f;
        #pragma unroll
        for (int j = 0; j < 16; ++j) {
            float p = expf(s[j] - mnew);
            Ps[r][c0 + j] = p;
            ts += p;
        }
        ts += __shfl_xor(ts, 1);
        ts += __shfl_xor(ts, 2);
        lsum = lsum * alpha + ts;
        m = mnew;
        #pragma unroll
        for (int i = 0; i < 16; ++i) oacc[i] *= alpha;
        __syncthreads();
        for (int c = 0; c < 64; ++c) {
            float pv = Ps[r][c];
            #pragma unroll
            for (int i = 0; i < 16; ++i) oacc[i] += pv * Vs[c][c0 + i];
        }
    }

    float invl = 1.0f / lsum;
    unsigned short* dst = attended + (((size_t)b * SEQ + (q0 + r)) * D_MODEL) + h * HDIM + c0;
    #pragma unroll
    for (int i = 0; i < 16; ++i) dst[i] = f2bf(oacc[i] * invl);
}

// ---------------------------------------------------------------------------
// Projection 1: t = attended @ Wout^T + b_out   (bf16 in, fp32 out)
// ---------------------------------------------------------------------------
__global__ void out_gemm1(const unsigned short* __restrict__ attended,
                          const float* __restrict__ Wout, const float* __restrict__ b_out,
                          float* __restrict__ t_out) {
    int ct = blockIdx.x;            // 0..15
    int rt = blockIdx.y;            // 0..63
    __shared__ float As[16][68];
    __shared__ float Bs[16][68];
    int tid = threadIdx.x;
    int tx = tid & 15, ty = tid >> 4;
    int arow = tid >> 2, akk = (tid & 3) * 4;
    const unsigned short* Arow = attended + (size_t)(rt * 64 + arow) * 1024;
    const float* Brow = Wout + (size_t)(ct * 64 + arow) * 1024;

    float acc[4][4] = {};
    for (int kt = 0; kt < 64; ++kt) {
        int k0 = kt * 16;
        ushort4 av = *(const ushort4*)(Arow + k0 + akk);
        float4 bv = *(const float4*)(Brow + k0 + akk);
        As[akk + 0][arow] = bf2f(av.x); As[akk + 1][arow] = bf2f(av.y);
        As[akk + 2][arow] = bf2f(av.z); As[akk + 3][arow] = bf2f(av.w);
        Bs[akk + 0][arow] = bv.x; Bs[akk + 1][arow] = bv.y;
        Bs[akk + 2][arow] = bv.z; Bs[akk + 3][arow] = bv.w;
        __syncthreads();
        #pragma unroll
        for (int kk = 0; kk < 16; ++kk) {
            float4 a = *(const float4*)&As[kk][ty * 4];
            float4 b = *(const float4*)&Bs[kk][tx * 4];
            acc[0][0] += a.x * b.x; acc[0][1] += a.x * b.y; acc[0][2] += a.x * b.z; acc[0][3] += a.x * b.w;
            acc[1][0] += a.y * b.x; acc[1][1] += a.y * b.y; acc[1][2] += a.y * b.z; acc[1][3] += a.y * b.w;
            acc[2][0] += a.z * b.x; acc[2][1] += a.z * b.y; acc[2][2] += a.z * b.z; acc[2][3] += a.z * b.w;
            acc[3][0] += a.w * b.x; acc[3][1] += a.w * b.y; acc[3][2] += a.w * b.z; acc[3][3] += a.w * b.w;
        }
        __syncthreads();
    }

    int jg = ct * 64 + tx * 4;
    int rg = rt * 64 + ty * 4;
    #pragma unroll
    for (int i = 0; i < 4; ++i) {
        #pragma unroll
        for (int j = 0; j < 4; ++j) {
            int col = jg + j;
            t_out[(size_t)(rg + i) * 1024 + col] = acc[i][j] + b_out[col];
        }
    }
}

// ---------------------------------------------------------------------------
// Projection 2: gz = t @ Wgate^T + b_gate ; out = sigmoid(gz)*t + (1-..)*res
// t is fp32.
// ---------------------------------------------------------------------------
__global__ void out_gemm2(const float* __restrict__ t_in,
                          const float* __restrict__ Wgate, const float* __restrict__ b_gate,
                          const float* __restrict__ residual, float* __restrict__ out) {
    int ct = blockIdx.x;            // 0..15
    int rt = blockIdx.y;            // 0..63
    __shared__ float As[16][68];
    __shared__ float Bs[16][68];
    int tid = threadIdx.x;
    int tx = tid & 15, ty = tid >> 4;
    int arow = tid >> 2, akk = (tid & 3) * 4;
    const float* Arow = t_in + (size_t)(rt * 64 + arow) * 1024;
    const float* Brow = Wgate + (size_t)(ct * 64 + arow) * 1024;

    float acc[4][4] = {};
    for (int kt = 0; kt < 64; ++kt) {
        int k0 = kt * 16;
        float4 av = *(const float4*)(Arow + k0 + akk);
        float4 bv = *(const float4*)(Brow + k0 + akk);
        As[akk + 0][arow] = av.x; As[akk + 1][arow] = av.y;
        As[akk + 2][arow] = av.z; As[akk + 3][arow] = av.w;
        Bs[akk + 0][arow] = bv.x; Bs[akk + 1][arow] = bv.y;
        Bs[akk + 2][arow] = bv.z; Bs[akk + 3][arow] = bv.w;
        __syncthreads();
        #pragma unroll
        for (int kk = 0; kk < 16; ++kk) {
            float4 a = *(const float4*)&As[kk][ty * 4];
            float4 b = *(const float4*)&Bs[kk][tx * 4];
            acc[0][0] += a.x * b.x; acc[0][1] += a.x * b.y; acc[0][2] += a.x * b.z; acc[0][3] += a.x * b.w;
            acc[1][0] += a.y * b.x; acc[1][1] += a.y * b.y; acc[1][2] += a.y * b.z; acc[1][3] += a.y * b.w;
            acc[2][0] += a.z * b.x; acc[2][1] += a.z * b.y; acc[2][2] += a.z * b.z; acc[2][3] += a.z * b.w;
            acc[3][0] += a.w * b.x; acc[3][1] += a.w * b.y; acc[3][2] += a.w * b.z; acc[3][3] += a.w * b.w;
        }
        __syncthreads();
    }

    int jg = ct * 64 + tx * 4;
    int rg = rt * 64 + ty * 4;
    #pragma unroll
    for (int i = 0; i < 4; ++i) {
        int row = rg + i;
        const float* trow = t_in + (size_t)row * 1024;
        const float* res  = residual + (size_t)row * 1024;
        #pragma unroll
        for (int j = 0; j < 4; ++j) {
            int col = jg + j;
            float gz = acc[i][j] + b_gate[col];
            float g = 1.0f / (1.0f + expf(-gz));
            float tv = trow[col];
            out[(size_t)row * 1024 + col] = g * tv + (1.0f - g) * res[col];
        }
    }
}

extern "C" void kernel_launch(void* const* d_in, const int* in_sizes, int n_in,
                              void* d_out, int out_size, void* d_ws, size_t ws_size,
                              hipStream_t stream) {
    const float* dec    = (const float*)d_in[0];
    const float* enc    = (const float*)d_in[1];
    const float* Wqkv   = (const float*)d_in[2];
    const float* Wout   = (const float*)d_in[3];
    const float* b_out  = (const float*)d_in[4];
    const float* Wgate  = (const float*)d_in[5];
    const float* b_gate = (const float*)d_in[6];
    const float* gamma  = (const float*)d_in[7];
    const float* beta   = (const float*)d_in[8];
    float* out = (float*)d_out;

    char* ws = (char*)d_ws;
    const size_t MB = 1024 * 1024;
    unsigned short* q_ln  = (unsigned short*)(ws + 0 * MB);    // 8 MB (dead after qkv_gemm)
    unsigned short* kv_ln = (unsigned short*)(ws + 8 * MB);    // 8 MB (dead after qkv_gemm)
    unsigned short* qb    = (unsigned short*)(ws + 16 * MB);   // 8 MB  (B,H,L,64)
    unsigned short* kb    = (unsigned short*)(ws + 24 * MB);   // 8 MB
    unsigned short* vb    = (unsigned short*)(ws + 32 * MB);   // 8 MB
    unsigned short* att   = (unsigned short*)(ws + 40 * MB);   // 8 MB  (B,L,1024)
    float* bias           = (float*)(ws + 48 * MB);            // 1 MB
    float* t_proj         = (float*)(ws + 0 * MB);             // 16 MB, overlays q_ln/kv_ln

    bias_kernel<<<1024, 256, 0, stream>>>(bias);
    ln_kernel<<<8192, 256, 0, stream>>>(dec, enc, gamma, beta, q_ln, kv_ln);
    qkv_gemm<<<dim3(48, 64), 256, 0, stream>>>(q_ln, kv_ln, Wqkv, qb, kb, vb);
    attn_kernel<<<dim3(8, 16, 8), 256, 0, stream>>>(qb, kb, vb, bias, att);
    out_gemm1<<<dim3(16, 64), 256, 0, stream>>>(att, Wout, b_out, t_proj);
    out_gemm2<<<dim3(16, 64), 256, 0, stream>>>(t_proj, Wgate, b_gate, dec, out);
}

// Round 3
// 729.571 us; speedup vs baseline: 1.4829x; 1.4829x over previous
//
#include <hip/hip_runtime.h>
#include <hip/hip_bf16.h>

#define D_MODEL 1024
#define NHEADS 16
#define HDIM 64
#define BATCH 8
#define SEQ 512
#define NROWS 4096          // BATCH*SEQ
#define SCALE 0.125f
#define LN_EPS 1e-5f

typedef __attribute__((ext_vector_type(8))) short bf16x8;      // 8 bf16 (4 VGPRs)
typedef __attribute__((ext_vector_type(4))) float f32x4;
typedef __attribute__((ext_vector_type(8))) unsigned short u16x8;

static __device__ __forceinline__ float bf2f(unsigned short u) {
    return __uint_as_float(((unsigned int)u) << 16);
}
static __device__ __forceinline__ unsigned short f2bf(float f) {
    unsigned int x = __float_as_uint(f);
    unsigned int r = (x + 0x7fffu + ((x >> 16) & 1u)) >> 16;   // RNE
    return (unsigned short)r;
}

// ---------------------------------------------------------------------------
// Bias: jax.image.resize(bias128, (512,512), 'bilinear')
// ---------------------------------------------------------------------------
static __device__ __forceinline__ float bias128(int a, int b) {
    float d = fabsf((float)(a - b));
    return expf(-d * 0.1f) - d * 0.05f;
}

__global__ void bias_kernel(float* __restrict__ bias) {
    int idx = blockIdx.x * 256 + threadIdx.x;
    if (idx >= 512 * 512) return;
    int qi = idx >> 9, kj = idx & 511;
    float fq = (qi + 0.5f) * 0.25f - 0.5f;
    float fk = (kj + 0.5f) * 0.25f - 0.5f;
    int iq = (int)floorf(fq); float tq = fq - (float)iq;
    int ik = (int)floorf(fk); float tk = fk - (float)ik;
    int iq0 = min(max(iq, 0), 127), iq1 = min(max(iq + 1, 0), 127);
    int ik0 = min(max(ik, 0), 127), ik1 = min(max(ik + 1, 0), 127);
    float v = (1.f - tq) * ((1.f - tk) * bias128(iq0, ik0) + tk * bias128(iq0, ik1))
            +        tq  * ((1.f - tk) * bias128(iq1, ik0) + tk * bias128(iq1, ik1));
    bias[idx] = v;
}

// ---------------------------------------------------------------------------
// LayerNorm of both streams -> bf16
// ---------------------------------------------------------------------------
__global__ void ln_kernel(const float* __restrict__ dec, const float* __restrict__ enc,
                          const float* __restrict__ gamma, const float* __restrict__ beta,
                          unsigned short* __restrict__ q_ln, unsigned short* __restrict__ kv_ln) {
    int row = blockIdx.x;                       // 0..8191
    const float* src = (row < NROWS) ? dec + (size_t)row * D_MODEL
                                     : enc + (size_t)(row - NROWS) * D_MODEL;
    unsigned short* dst = (row < NROWS) ? q_ln + (size_t)row * D_MODEL
                                        : kv_ln + (size_t)(row - NROWS) * D_MODEL;
    int t = threadIdx.x;
    float4 x = ((const float4*)src)[t];
    float s  = x.x + x.y + x.z + x.w;
    float ss = x.x * x.x + x.y * x.y + x.z * x.z + x.w * x.w;
    #pragma unroll
    for (int off = 32; off > 0; off >>= 1) {
        s  += __shfl_down(s, off);
        ss += __shfl_down(ss, off);
    }
    __shared__ float red_s[4], red_ss[4];
    int wid = t >> 6, lane = t & 63;
    if (lane == 0) { red_s[wid] = s; red_ss[wid] = ss; }
    __syncthreads();
    if (t == 0) {
        float S = red_s[0] + red_s[1] + red_s[2] + red_s[3];
        float SS = red_ss[0] + red_ss[1] + red_ss[2] + red_ss[3];
        red_s[0] = S; red_ss[0] = SS;
    }
    __syncthreads();
    float mu  = red_s[0] * (1.0f / 1024.0f);
    float var = red_ss[0] * (1.0f / 1024.0f) - mu * mu;
    float rstd = rsqrtf(var + LN_EPS);
    float4 g = ((const float4*)gamma)[t];
    float4 bb = ((const float4*)beta)[t];
    ushort4 u;
    u.x = f2bf((x.x - mu) * rstd * g.x + bb.x);
    u.y = f2bf((x.y - mu) * rstd * g.y + bb.y);
    u.z = f2bf((x.z - mu) * rstd * g.z + bb.z);
    u.w = f2bf((x.w - mu) * rstd * g.w + bb.w);
    ((ushort4*)dst)[t] = u;
}

// ---------------------------------------------------------------------------
// QKV GEMM (fp32 VALU) unchanged from round 2 (verified)
// ---------------------------------------------------------------------------
__global__ void qkv_gemm(const unsigned short* __restrict__ q_ln,
                         const unsigned short* __restrict__ kv_ln,
                         const float* __restrict__ Wqkv,
                         unsigned short* __restrict__ qo,
                         unsigned short* __restrict__ ko,
                         unsigned short* __restrict__ vo) {
    int ct = blockIdx.x;            // 0..47
    int rt = blockIdx.y;            // 0..63
    int jbase = ct * 64;
    int section = jbase >> 10;      // 0=q 1=k 2=v
    int h = (jbase & 1023) >> 6;
    const unsigned short* A = (section == 0) ? q_ln : kv_ln;

    __shared__ float As[16][68];
    __shared__ float Bs[16][68];
    __shared__ float Cs[64][65];

    int tid = threadIdx.x;
    int tx = tid & 15, ty = tid >> 4;
    int arow = tid >> 2;            // 0..63
    int akk = (tid & 3) * 4;        // 0,4,8,12
    const unsigned short* Arow = A + (size_t)(rt * 64 + arow) * 1024;
    const float* Brow = Wqkv + (size_t)(jbase + arow) * 1024;

    float acc[4][4] = {};
    for (int kt = 0; kt < 64; ++kt) {
        int k0 = kt * 16;
        ushort4 av = *(const ushort4*)(Arow + k0 + akk);
        float4 bv = *(const float4*)(Brow + k0 + akk);
        As[akk + 0][arow] = bf2f(av.x);
        As[akk + 1][arow] = bf2f(av.y);
        As[akk + 2][arow] = bf2f(av.z);
        As[akk + 3][arow] = bf2f(av.w);
        Bs[akk + 0][arow] = bv.x;
        Bs[akk + 1][arow] = bv.y;
        Bs[akk + 2][arow] = bv.z;
        Bs[akk + 3][arow] = bv.w;
        __syncthreads();
        #pragma unroll
        for (int kk = 0; kk < 16; ++kk) {
            float4 a = *(const float4*)&As[kk][ty * 4];
            float4 b = *(const float4*)&Bs[kk][tx * 4];
            acc[0][0] += a.x * b.x; acc[0][1] += a.x * b.y; acc[0][2] += a.x * b.z; acc[0][3] += a.x * b.w;
            acc[1][0] += a.y * b.x; acc[1][1] += a.y * b.y; acc[1][2] += a.y * b.z; acc[1][3] += a.y * b.w;
            acc[2][0] += a.z * b.x; acc[2][1] += a.z * b.y; acc[2][2] += a.z * b.z; acc[2][3] += a.z * b.w;
            acc[3][0] += a.w * b.x; acc[3][1] += a.w * b.y; acc[3][2] += a.w * b.z; acc[3][3] += a.w * b.w;
        }
        __syncthreads();
    }
    #pragma unroll
    for (int i = 0; i < 4; ++i)
        #pragma unroll
        for (int j = 0; j < 4; ++j)
            Cs[ty * 4 + i][tx * 4 + j] = acc[i][j];
    __syncthreads();

    int r = tid >> 2;
    int d0 = (tid & 3) * 16;
    int grow = rt * 64 + r;
    int b = grow >> 9, l = grow & 511;
    unsigned short* outp = (section == 0) ? qo : (section == 1) ? ko : vo;
    size_t obase = (((size_t)b * NHEADS + h) * SEQ + l) * HDIM;

    if (section == 2) {
        #pragma unroll
        for (int j = 0; j < 16; ++j)
            outp[obase + d0 + j] = f2bf(Cs[r][d0 + j]);
    } else {
        #pragma unroll
        for (int j = 0; j < 16; ++j) {
            int d = d0 + j;
            int f = (d < 32) ? d : d - 32;
            float inv = expf(-0.2878231366f * (float)f);   // 10000^(-f/32)
            float ang = (float)l * inv;
            float c = cosf(ang), s = sinf(ang);
            float val = (d < 32) ? (Cs[r][d] * c - Cs[r][d + 32] * s)
                                 : (Cs[r][d - 32] * s + Cs[r][d] * c);
            outp[obase + d] = f2bf(val);
        }
    }
}

// ---------------------------------------------------------------------------
// Flash attention, bf16 MFMA (16x16x32).
// Block: 256 thr = 4 waves; one (b,h), 64 q rows. Wave w owns q rows
// [w*16, w*16+16). KV iterated in 64-row tiles.
//
// Layout facts used (HW-verified per guide §3 / m89/m91/m120):
//   A-frag:  a[j] = A[m = lane&15][k = (lane>>4)*8 + j]
//   B-frag:  b[j] = B[k = (lane>>4)*8 + j][n = lane&15]
//   C/D:     D[row = (lane>>4)*4 + reg][col = lane&15]
//
// QK^T: A=Q (regs), B=K^T read from row-major Ks. S in C layout.
// Softmax: row = q = quad*4+reg -> shfl_xor 1/2/4/8 within quad.
// PV computed as O^T = V^T * P^T:
//   A = V^T from Vt (V staged transposed), B = P^T read from row-major Ps.
//   O^T: row = d, col = q=lane&15 -> per-lane alpha/invl via LDS broadcast.
// ---------------------------------------------------------------------------
#define KSTR 72   // LDS row stride in bf16 elems (144B, 16B-aligned, non-pow2)

__global__ __launch_bounds__(256)
void attn_kernel(const unsigned short* __restrict__ q,
                 const unsigned short* __restrict__ k,
                 const unsigned short* __restrict__ v,
                 const float* __restrict__ bias,
                 unsigned short* __restrict__ attended) {
    int qt = blockIdx.x, h = blockIdx.y, b = blockIdx.z;
    __shared__ unsigned short Ks[64 * KSTR];
    __shared__ unsigned short Vt[64 * KSTR];
    __shared__ unsigned short Ps[64 * KSTR];
    __shared__ float af[64];
    __shared__ float lf[64];

    int tid = threadIdx.x;
    int wave = tid >> 6, lane = tid & 63;
    int quad = lane >> 4, c = lane & 15;
    int wb = wave * 16;                 // wave's q-row base in the 64-tile
    size_t headbase = (((size_t)b * NHEADS + h) * SEQ) * HDIM;
    int q0 = qt * 64;

    // Q fragments (constant over kv loop): rows q0+wb+c
    const unsigned short* qrow = q + headbase + (size_t)(q0 + wb + c) * HDIM;
    bf16x8 aq0 = *(const bf16x8*)(qrow + quad * 8);
    bf16x8 aq1 = *(const bf16x8*)(qrow + 32 + quad * 8);

    int sr = tid >> 2, sc0 = (tid & 3) * 16;    // staging: row, col-base

    f32x4 oacc[4];                      // O^T: row d=16t+quad*4+reg, col q=wb+c
    #pragma unroll
    for (int t = 0; t < 4; ++t) oacc[t] = (f32x4)0.f;
    float mrow[4], lrow[4];
    #pragma unroll
    for (int r = 0; r < 4; ++r) { mrow[r] = -1e30f; lrow[r] = 0.f; }

    for (int kt = 0; kt < 8; ++kt) {
        int kv0 = kt * 64;
        __syncthreads();                // prior tile's Ks/Vt reads complete
        {
            const unsigned short* krow = k + headbase + (size_t)(kv0 + sr) * HDIM + sc0;
            const unsigned short* vrow = v + headbase + (size_t)(kv0 + sr) * HDIM + sc0;
            u16x8 ka = *(const u16x8*)(krow);
            u16x8 kb2 = *(const u16x8*)(krow + 8);
            u16x8 va = *(const u16x8*)(vrow);
            u16x8 vb2 = *(const u16x8*)(vrow + 8);
            *(u16x8*)&Ks[sr * KSTR + sc0] = ka;
            *(u16x8*)&Ks[sr * KSTR + sc0 + 8] = kb2;
            #pragma unroll
            for (int j = 0; j < 8; ++j) Vt[(sc0 + j) * KSTR + sr] = va[j];
            #pragma unroll
            for (int j = 0; j < 8; ++j) Vt[(sc0 + 8 + j) * KSTR + sr] = vb2[j];
        }
        __syncthreads();

        // ---- S = Q K^T  (per wave: 16 q rows x 64 kv) ----
        f32x4 sacc[4];
        #pragma unroll
        for (int nt = 0; nt < 4; ++nt) {
            const unsigned short* kbase = &Ks[(nt * 16 + c) * KSTR];
            bf16x8 b0 = *(const bf16x8*)(kbase + quad * 8);
            bf16x8 b1 = *(const bf16x8*)(kbase + 32 + quad * 8);
            f32x4 acc = (f32x4)0.f;
            acc = __builtin_amdgcn_mfma_f32_16x16x32_bf16(aq0, b0, acc, 0, 0, 0);
            acc = __builtin_amdgcn_mfma_f32_16x16x32_bf16(aq1, b1, acc, 0, 0, 0);
            sacc[nt] = acc;
        }

        // ---- scale + bias + online softmax (C layout) ----
        const float* bbase = bias + (size_t)(q0 + wb + quad * 4) * 512 + kv0 + c;
        float tmax[4];
        #pragma unroll
        for (int r = 0; r < 4; ++r) tmax[r] = -1e30f;
        #pragma unroll
        for (int nt = 0; nt < 4; ++nt)
            #pragma unroll
            for (int r = 0; r < 4; ++r) {
                float s = sacc[nt][r] * SCALE + bbase[(size_t)r * 512 + nt * 16];
                sacc[nt][r] = s;
                tmax[r] = fmaxf(tmax[r], s);
            }
        #pragma unroll
        for (int r = 0; r < 4; ++r) {
            float t = tmax[r];
            t = fmaxf(t, __shfl_xor(t, 1));
            t = fmaxf(t, __shfl_xor(t, 2));
            t = fmaxf(t, __shfl_xor(t, 4));
            t = fmaxf(t, __shfl_xor(t, 8));
            tmax[r] = t;
        }
        float alpha[4];
        #pragma unroll
        for (int r = 0; r < 4; ++r) {
            float mnew = fmaxf(mrow[r], tmax[r]);
            alpha[r] = __expf(mrow[r] - mnew);
            mrow[r] = mnew;
        }
        float tsum[4];
        #pragma unroll
        for (int r = 0; r < 4; ++r) tsum[r] = 0.f;
        #pragma unroll
        for (int nt = 0; nt < 4; ++nt)
            #pragma unroll
            for (int r = 0; r < 4; ++r) {
                float p = __expf(sacc[nt][r] - mrow[r]);
                tsum[r] += p;
                Ps[(wb + quad * 4 + r) * KSTR + nt * 16 + c] = f2bf(p);
            }
        #pragma unroll
        for (int r = 0; r < 4; ++r) {
            float t = tsum[r];
            t += __shfl_xor(t, 1);
            t += __shfl_xor(t, 2);
            t += __shfl_xor(t, 4);
            t += __shfl_xor(t, 8);
            lrow[r] = lrow[r] * alpha[r] + t;
        }
        // broadcast alpha (per q row) quad-layout -> lane-layout, intra-wave
        if (c == 0) {
            f32x4 av;
            av[0] = alpha[0]; av[1] = alpha[1]; av[2] = alpha[2]; av[3] = alpha[3];
            *(f32x4*)&af[wb + quad * 4] = av;
        }
        float myalpha = af[wb + c];
        #pragma unroll
        for (int t = 0; t < 4; ++t) oacc[t] *= myalpha;

        // ---- O^T += V^T P^T ----
        bf16x8 pb0 = *(const bf16x8*)&Ps[(wb + c) * KSTR + quad * 8];
        bf16x8 pb1 = *(const bf16x8*)&Ps[(wb + c) * KSTR + 32 + quad * 8];
        #pragma unroll
        for (int t = 0; t < 4; ++t) {
            const unsigned short* vbase = &Vt[(t * 16 + c) * KSTR];
            bf16x8 a0 = *(const bf16x8*)(vbase + quad * 8);
            bf16x8 a1 = *(const bf16x8*)(vbase + 32 + quad * 8);
            oacc[t] = __builtin_amdgcn_mfma_f32_16x16x32_bf16(a0, pb0, oacc[t], 0, 0, 0);
            oacc[t] = __builtin_amdgcn_mfma_f32_16x16x32_bf16(a1, pb1, oacc[t], 0, 0, 0);
        }
    }

    // final 1/l broadcast and store
    if (c == 0) {
        f32x4 lv;
        lv[0] = lrow[0]; lv[1] = lrow[1]; lv[2] = lrow[2]; lv[3] = lrow[3];
        *(f32x4*)&lf[wb + quad * 4] = lv;
    }
    float invl = 1.0f / lf[wb + c];
    unsigned short* drow = attended + ((size_t)b * SEQ + (q0 + wb + c)) * D_MODEL + h * HDIM;
    #pragma unroll
    for (int t = 0; t < 4; ++t) {
        ushort4 o;
        o.x = f2bf(oacc[t][0] * invl);
        o.y = f2bf(oacc[t][1] * invl);
        o.z = f2bf(oacc[t][2] * invl);
        o.w = f2bf(oacc[t][3] * invl);
        *(ushort4*)(drow + t * 16 + quad * 4) = o;
    }
}

// ---------------------------------------------------------------------------
// Projection 1: t = attended @ Wout^T + b_out   (bf16 in, fp32 out)
// ---------------------------------------------------------------------------
__global__ void out_gemm1(const unsigned short* __restrict__ attended,
                          const float* __restrict__ Wout, const float* __restrict__ b_out,
                          float* __restrict__ t_out) {
    int ct = blockIdx.x;            // 0..15
    int rt = blockIdx.y;            // 0..63
    __shared__ float As[16][68];
    __shared__ float Bs[16][68];
    int tid = threadIdx.x;
    int tx = tid & 15, ty = tid >> 4;
    int arow = tid >> 2, akk = (tid & 3) * 4;
    const unsigned short* Arow = attended + (size_t)(rt * 64 + arow) * 1024;
    const float* Brow = Wout + (size_t)(ct * 64 + arow) * 1024;

    float acc[4][4] = {};
    for (int kt = 0; kt < 64; ++kt) {
        int k0 = kt * 16;
        ushort4 av = *(const ushort4*)(Arow + k0 + akk);
        float4 bv = *(const float4*)(Brow + k0 + akk);
        As[akk + 0][arow] = bf2f(av.x); As[akk + 1][arow] = bf2f(av.y);
        As[akk + 2][arow] = bf2f(av.z); As[akk + 3][arow] = bf2f(av.w);
        Bs[akk + 0][arow] = bv.x; Bs[akk + 1][arow] = bv.y;
        Bs[akk + 2][arow] = bv.z; Bs[akk + 3][arow] = bv.w;
        __syncthreads();
        #pragma unroll
        for (int kk = 0; kk < 16; ++kk) {
            float4 a = *(const float4*)&As[kk][ty * 4];
            float4 b = *(const float4*)&Bs[kk][tx * 4];
            acc[0][0] += a.x * b.x; acc[0][1] += a.x * b.y; acc[0][2] += a.x * b.z; acc[0][3] += a.x * b.w;
            acc[1][0] += a.y * b.x; acc[1][1] += a.y * b.y; acc[1][2] += a.y * b.z; acc[1][3] += a.y * b.w;
            acc[2][0] += a.z * b.x; acc[2][1] += a.z * b.y; acc[2][2] += a.z * b.z; acc[2][3] += a.z * b.w;
            acc[3][0] += a.w * b.x; acc[3][1] += a.w * b.y; acc[3][2] += a.w * b.z; acc[3][3] += a.w * b.w;
        }
        __syncthreads();
    }

    int jg = ct * 64 + tx * 4;
    int rg = rt * 64 + ty * 4;
    #pragma unroll
    for (int i = 0; i < 4; ++i) {
        #pragma unroll
        for (int j = 0; j < 4; ++j) {
            int col = jg + j;
            t_out[(size_t)(rg + i) * 1024 + col] = acc[i][j] + b_out[col];
        }
    }
}

// ---------------------------------------------------------------------------
// Projection 2: gz = t @ Wgate^T + b_gate ; out = sigmoid(gz)*t + (1-..)*res
// ---------------------------------------------------------------------------
__global__ void out_gemm2(const float* __restrict__ t_in,
                          const float* __restrict__ Wgate, const float* __restrict__ b_gate,
                          const float* __restrict__ residual, float* __restrict__ out) {
    int ct = blockIdx.x;            // 0..15
    int rt = blockIdx.y;            // 0..63
    __shared__ float As[16][68];
    __shared__ float Bs[16][68];
    int tid = threadIdx.x;
    int tx = tid & 15, ty = tid >> 4;
    int arow = tid >> 2, akk = (tid & 3) * 4;
    const float* Arow = t_in + (size_t)(rt * 64 + arow) * 1024;
    const float* Brow = Wgate + (size_t)(ct * 64 + arow) * 1024;

    float acc[4][4] = {};
    for (int kt = 0; kt < 64; ++kt) {
        int k0 = kt * 16;
        float4 av = *(const float4*)(Arow + k0 + akk);
        float4 bv = *(const float4*)(Brow + k0 + akk);
        As[akk + 0][arow] = av.x; As[akk + 1][arow] = av.y;
        As[akk + 2][arow] = av.z; As[akk + 3][arow] = av.w;
        Bs[akk + 0][arow] = bv.x; Bs[akk + 1][arow] = bv.y;
        Bs[akk + 2][arow] = bv.z; Bs[akk + 3][arow] = bv.w;
        __syncthreads();
        #pragma unroll
        for (int kk = 0; kk < 16; ++kk) {
            float4 a = *(const float4*)&As[kk][ty * 4];
            float4 b = *(const float4*)&Bs[kk][tx * 4];
            acc[0][0] += a.x * b.x; acc[0][1] += a.x * b.y; acc[0][2] += a.x * b.z; acc[0][3] += a.x * b.w;
            acc[1][0] += a.y * b.x; acc[1][1] += a.y * b.y; acc[1][2] += a.y * b.z; acc[1][3] += a.y * b.w;
            acc[2][0] += a.z * b.x; acc[2][1] += a.z * b.y; acc[2][2] += a.z * b.z; acc[2][3] += a.z * b.w;
            acc[3][0] += a.w * b.x; acc[3][1] += a.w * b.y; acc[3][2] += a.w * b.z; acc[3][3] += a.w * b.w;
        }
        __syncthreads();
    }

    int jg = ct * 64 + tx * 4;
    int rg = rt * 64 + ty * 4;
    #pragma unroll
    for (int i = 0; i < 4; ++i) {
        int row = rg + i;
        const float* trow = t_in + (size_t)row * 1024;
        const float* res  = residual + (size_t)row * 1024;
        #pragma unroll
        for (int j = 0; j < 4; ++j) {
            int col = jg + j;
            float gz = acc[i][j] + b_gate[col];
            float g = 1.0f / (1.0f + expf(-gz));
            float tv = trow[col];
            out[(size_t)row * 1024 + col] = g * tv + (1.0f - g) * res[col];
        }
    }
}

extern "C" void kernel_launch(void* const* d_in, const int* in_sizes, int n_in,
                              void* d_out, int out_size, void* d_ws, size_t ws_size,
                              hipStream_t stream) {
    const float* dec    = (const float*)d_in[0];
    const float* enc    = (const float*)d_in[1];
    const float* Wqkv   = (const float*)d_in[2];
    const float* Wout   = (const float*)d_in[3];
    const float* b_out  = (const float*)d_in[4];
    const float* Wgate  = (const float*)d_in[5];
    const float* b_gate = (const float*)d_in[6];
    const float* gamma  = (const float*)d_in[7];
    const float* beta   = (const float*)d_in[8];
    float* out = (float*)d_out;

    char* ws = (char*)d_ws;
    const size_t MB = 1024 * 1024;
    unsigned short* q_ln  = (unsigned short*)(ws + 0 * MB);    // 8 MB (dead after qkv_gemm)
    unsigned short* kv_ln = (unsigned short*)(ws + 8 * MB);    // 8 MB (dead after qkv_gemm)
    unsigned short* qb    = (unsigned short*)(ws + 16 * MB);   // 8 MB  (B,H,L,64)
    unsigned short* kb    = (unsigned short*)(ws + 24 * MB);   // 8 MB
    unsigned short* vb    = (unsigned short*)(ws + 32 * MB);   // 8 MB
    unsigned short* att   = (unsigned short*)(ws + 40 * MB);   // 8 MB  (B,L,1024)
    float* bias           = (float*)(ws + 48 * MB);            // 1 MB
    float* t_proj         = (float*)(ws + 0 * MB);             // 16 MB, overlays q_ln/kv_ln

    bias_kernel<<<1024, 256, 0, stream>>>(bias);
    ln_kernel<<<8192, 256, 0, stream>>>(dec, enc, gamma, beta, q_ln, kv_ln);
    qkv_gemm<<<dim3(48, 64), 256, 0, stream>>>(q_ln, kv_ln, Wqkv, qb, kb, vb);
    attn_kernel<<<dim3(8, 16, 8), 256, 0, stream>>>(qb, kb, vb, bias, att);
    out_gemm1<<<dim3(16, 64), 256, 0, stream>>>(att, Wout, b_out, t_proj);
    out_gemm2<<<dim3(16, 64), 256, 0, stream>>>(t_proj, Wgate, b_gate, dec, out);
}

// Round 4
// 560.490 us; speedup vs baseline: 1.9302x; 1.3017x over previous
//
#include <hip/hip_runtime.h>
#include <hip/hip_bf16.h>

#define D_MODEL 1024
#define NHEADS 16
#define HDIM 64
#define BATCH 8
#define SEQ 512
#define NROWS 4096          // BATCH*SEQ
#define SCALE 0.125f
#define LN_EPS 1e-5f

typedef __attribute__((ext_vector_type(8))) short bf16x8;      // 8 bf16 (4 VGPRs)
typedef __attribute__((ext_vector_type(4))) float f32x4;
typedef __attribute__((ext_vector_type(8))) unsigned short u16x8;

static __device__ __forceinline__ float bf2f(unsigned short u) {
    return __uint_as_float(((unsigned int)u) << 16);
}
static __device__ __forceinline__ unsigned short f2bf(float f) {
    unsigned int x = __float_as_uint(f);
    unsigned int r = (x + 0x7fffu + ((x >> 16) & 1u)) >> 16;   // RNE
    return (unsigned short)r;
}

// ---------------------------------------------------------------------------
// fp32 -> bf16 bulk convert (weights)
// ---------------------------------------------------------------------------
__global__ void f32_to_bf16(const float* __restrict__ src, unsigned short* __restrict__ dst, int n4) {
    int idx = blockIdx.x * 256 + threadIdx.x;
    if (idx >= n4) return;
    float4 v = ((const float4*)src)[idx];
    ushort4 u;
    u.x = f2bf(v.x); u.y = f2bf(v.y); u.z = f2bf(v.z); u.w = f2bf(v.w);
    ((ushort4*)dst)[idx] = u;
}

// ---------------------------------------------------------------------------
// Bias: jax.image.resize(bias128, (512,512), 'bilinear')
// ---------------------------------------------------------------------------
static __device__ __forceinline__ float bias128(int a, int b) {
    float d = fabsf((float)(a - b));
    return expf(-d * 0.1f) - d * 0.05f;
}

__global__ void bias_kernel(float* __restrict__ bias) {
    int idx = blockIdx.x * 256 + threadIdx.x;
    if (idx >= 512 * 512) return;
    int qi = idx >> 9, kj = idx & 511;
    float fq = (qi + 0.5f) * 0.25f - 0.5f;
    float fk = (kj + 0.5f) * 0.25f - 0.5f;
    int iq = (int)floorf(fq); float tq = fq - (float)iq;
    int ik = (int)floorf(fk); float tk = fk - (float)ik;
    int iq0 = min(max(iq, 0), 127), iq1 = min(max(iq + 1, 0), 127);
    int ik0 = min(max(ik, 0), 127), ik1 = min(max(ik + 1, 0), 127);
    float v = (1.f - tq) * ((1.f - tk) * bias128(iq0, ik0) + tk * bias128(iq0, ik1))
            +        tq  * ((1.f - tk) * bias128(iq1, ik0) + tk * bias128(iq1, ik1));
    bias[idx] = v;
}

// ---------------------------------------------------------------------------
// LayerNorm of both streams -> bf16
// ---------------------------------------------------------------------------
__global__ void ln_kernel(const float* __restrict__ dec, const float* __restrict__ enc,
                          const float* __restrict__ gamma, const float* __restrict__ beta,
                          unsigned short* __restrict__ q_ln, unsigned short* __restrict__ kv_ln) {
    int row = blockIdx.x;                       // 0..8191
    const float* src = (row < NROWS) ? dec + (size_t)row * D_MODEL
                                     : enc + (size_t)(row - NROWS) * D_MODEL;
    unsigned short* dst = (row < NROWS) ? q_ln + (size_t)row * D_MODEL
                                        : kv_ln + (size_t)(row - NROWS) * D_MODEL;
    int t = threadIdx.x;
    float4 x = ((const float4*)src)[t];
    float s  = x.x + x.y + x.z + x.w;
    float ss = x.x * x.x + x.y * x.y + x.z * x.z + x.w * x.w;
    #pragma unroll
    for (int off = 32; off > 0; off >>= 1) {
        s  += __shfl_down(s, off);
        ss += __shfl_down(ss, off);
    }
    __shared__ float red_s[4], red_ss[4];
    int wid = t >> 6, lane = t & 63;
    if (lane == 0) { red_s[wid] = s; red_ss[wid] = ss; }
    __syncthreads();
    if (t == 0) {
        float S = red_s[0] + red_s[1] + red_s[2] + red_s[3];
        float SS = red_ss[0] + red_ss[1] + red_ss[2] + red_ss[3];
        red_s[0] = S; red_ss[0] = SS;
    }
    __syncthreads();
    float mu  = red_s[0] * (1.0f / 1024.0f);
    float var = red_ss[0] * (1.0f / 1024.0f) - mu * mu;
    float rstd = rsqrtf(var + LN_EPS);
    float4 g = ((const float4*)gamma)[t];
    float4 bb = ((const float4*)beta)[t];
    ushort4 u;
    u.x = f2bf((x.x - mu) * rstd * g.x + bb.x);
    u.y = f2bf((x.y - mu) * rstd * g.y + bb.y);
    u.z = f2bf((x.z - mu) * rstd * g.z + bb.z);
    u.w = f2bf((x.w - mu) * rstd * g.w + bb.w);
    ((ushort4*)dst)[t] = u;
}

// ===========================================================================
// Shared MFMA GEMM pattern: C(128x128) = A(128xK) @ W^T(128xK), bf16 in.
// 256 thr = 4 waves (2x2); wave does 64x64 as 4x4 MFMA 16x16 tiles.
// BK=64 per stage (2 K-chunks of 32). LDS rows padded to 72 elems.
// Fragment layouts (HW-verified, guide §3):
//   A-frag a[j] = A[m=lane&15][k=quad*8+j]; B-frag b[j] = B^T row n, same;
//   C/D: D[row=quad*4+reg][col=lane&15].
// ===========================================================================
#define GSTR 72

#define GEMM_MAIN_LOOP(Aptr, Bptr)                                             \
    __shared__ unsigned short As[128 * GSTR];                                  \
    __shared__ unsigned short Bs[128 * GSTR];                                  \
    int tid = threadIdx.x;                                                     \
    int wave = tid >> 6, lane = tid & 63, quad = lane >> 4, c = lane & 15;     \
    int wr = wave >> 1, wc = wave & 1;                                         \
    int colg = tid & 7, r0 = tid >> 3;                                         \
    const unsigned short* Ab = (Aptr) + (size_t)(rt * 128 + r0) * 1024 + colg * 8; \
    const unsigned short* Bb = (Bptr) + (size_t)(ct * 128 + r0) * 1024 + colg * 8; \
    f32x4 acc[4][4];                                                           \
    _Pragma("unroll")                                                          \
    for (int i = 0; i < 4; ++i)                                                \
        _Pragma("unroll")                                                      \
        for (int j = 0; j < 4; ++j) acc[i][j] = (f32x4)0.f;                    \
    for (int kt = 0; kt < 16; ++kt) {                                          \
        int k0 = kt * 64;                                                      \
        __syncthreads();                                                       \
        _Pragma("unroll")                                                      \
        for (int j = 0; j < 4; ++j) {                                          \
            *(u16x8*)&As[(r0 + j * 32) * GSTR + colg * 8] =                    \
                *(const u16x8*)(Ab + (size_t)j * 32 * 1024 + k0);              \
            *(u16x8*)&Bs[(r0 + j * 32) * GSTR + colg * 8] =                    \
                *(const u16x8*)(Bb + (size_t)j * 32 * 1024 + k0);              \
        }                                                                      \
        __syncthreads();                                                       \
        _Pragma("unroll")                                                      \
        for (int kh = 0; kh < 2; ++kh) {                                       \
            bf16x8 af[4], bfr[4];                                              \
            _Pragma("unroll")                                                  \
            for (int i = 0; i < 4; ++i)                                        \
                af[i] = *(const bf16x8*)&As[(wr * 64 + i * 16 + c) * GSTR + kh * 32 + quad * 8]; \
            _Pragma("unroll")                                                  \
            for (int j = 0; j < 4; ++j)                                        \
                bfr[j] = *(const bf16x8*)&Bs[(wc * 64 + j * 16 + c) * GSTR + kh * 32 + quad * 8]; \
            _Pragma("unroll")                                                  \
            for (int i = 0; i < 4; ++i)                                        \
                _Pragma("unroll")                                              \
                for (int j = 0; j < 4; ++j)                                    \
                    acc[i][j] = __builtin_amdgcn_mfma_f32_16x16x32_bf16(af[i], bfr[j], acc[i][j], 0, 0, 0); \
        }                                                                      \
    }

// ---------------------------------------------------------------------------
// QKV GEMM (MFMA) + fused RoPE, scatter to (B,H,L,64) bf16
// grid (24, 32): ct covers n (3072), rt covers m (4096)
// ---------------------------------------------------------------------------
__global__ __launch_bounds__(256)
void qkv_gemm_mfma(const unsigned short* __restrict__ q_ln,
                   const unsigned short* __restrict__ kv_ln,
                   const unsigned short* __restrict__ Wb,
                   unsigned short* __restrict__ qo,
                   unsigned short* __restrict__ ko,
                   unsigned short* __restrict__ vo) {
    int ct = blockIdx.x, rt = blockIdx.y;
    int n0 = ct * 128;
    int section = n0 >> 10;         // 0=q 1=k 2=v (uniform per block)
    const unsigned short* A = (section == 0) ? q_ln : kv_ln;

    GEMM_MAIN_LOOP(A, Wb)

    int h = ((n0 & 1023) >> 6) + wc;          // wave covers exactly one head
    unsigned short* outp = (section == 0) ? qo : (section == 1) ? ko : vo;

    if (section == 2) {
        #pragma unroll
        for (int i = 0; i < 4; ++i)
            #pragma unroll
            for (int reg = 0; reg < 4; ++reg) {
                int mm = rt * 128 + wr * 64 + i * 16 + quad * 4 + reg;
                int b = mm >> 9, l = mm & 511;
                size_t obase = (((size_t)b * NHEADS + h) * SEQ + l) * HDIM;
                #pragma unroll
                for (int j = 0; j < 4; ++j)
                    outp[obase + j * 16 + c] = f2bf(acc[i][j][reg]);
            }
    } else {
        float inv0 = expf(-0.2878231366f * (float)c);          // f = c
        float inv1 = expf(-0.2878231366f * (float)(16 + c));   // f = 16+c
        #pragma unroll
        for (int i = 0; i < 4; ++i)
            #pragma unroll
            for (int reg = 0; reg < 4; ++reg) {
                int mm = rt * 128 + wr * 64 + i * 16 + quad * 4 + reg;
                int b = mm >> 9, l = mm & 511;
                size_t obase = (((size_t)b * NHEADS + h) * SEQ + l) * HDIM;
                float fl = (float)l;
                {   // d = c (tile j=0) pairs with d+32 (tile j=2)
                    float ang = fl * inv0;
                    float cc = cosf(ang), ss = sinf(ang);
                    float e = acc[i][0][reg], o = acc[i][2][reg];
                    outp[obase + c]      = f2bf(e * cc - o * ss);
                    outp[obase + 32 + c] = f2bf(e * ss + o * cc);
                }
                {   // d = 16+c (tile j=1) pairs with d+32 (tile j=3)
                    float ang = fl * inv1;
                    float cc = cosf(ang), ss = sinf(ang);
                    float e = acc[i][1][reg], o = acc[i][3][reg];
                    outp[obase + 16 + c] = f2bf(e * cc - o * ss);
                    outp[obase + 48 + c] = f2bf(e * ss + o * cc);
                }
            }
    }
}

// ---------------------------------------------------------------------------
// Projection 1 (MFMA): t = att @ Wout^T + b_out -> fp32 t_proj + bf16 t_bf
// grid (8, 32)
// ---------------------------------------------------------------------------
__global__ __launch_bounds__(256)
void out_gemm1_mfma(const unsigned short* __restrict__ att,
                    const unsigned short* __restrict__ Wob,
                    const float* __restrict__ b_out,
                    float* __restrict__ t_proj,
                    unsigned short* __restrict__ t_bf) {
    int ct = blockIdx.x, rt = blockIdx.y;

    GEMM_MAIN_LOOP(att, Wob)

    #pragma unroll
    for (int j = 0; j < 4; ++j) {
        int n = ct * 128 + wc * 64 + j * 16 + c;
        float bo = b_out[n];
        #pragma unroll
        for (int i = 0; i < 4; ++i)
            #pragma unroll
            for (int reg = 0; reg < 4; ++reg) {
                int mm = rt * 128 + wr * 64 + i * 16 + quad * 4 + reg;
                float v = acc[i][j][reg] + bo;
                t_proj[(size_t)mm * 1024 + n] = v;
                t_bf[(size_t)mm * 1024 + n] = f2bf(v);
            }
    }
}

// ---------------------------------------------------------------------------
// Projection 2 (MFMA): gz = t_bf @ Wgate^T + b_gate;
// out = sigmoid(gz)*t + (1-sigmoid)*residual
// grid (8, 32)
// ---------------------------------------------------------------------------
__global__ __launch_bounds__(256)
void out_gemm2_mfma(const unsigned short* __restrict__ t_bf,
                    const unsigned short* __restrict__ Wgb,
                    const float* __restrict__ b_gate,
                    const float* __restrict__ t_proj,
                    const float* __restrict__ residual,
                    float* __restrict__ out) {
    int ct = blockIdx.x, rt = blockIdx.y;

    GEMM_MAIN_LOOP(t_bf, Wgb)

    #pragma unroll
    for (int j = 0; j < 4; ++j) {
        int n = ct * 128 + wc * 64 + j * 16 + c;
        float bg = b_gate[n];
        #pragma unroll
        for (int i = 0; i < 4; ++i)
            #pragma unroll
            for (int reg = 0; reg < 4; ++reg) {
                int mm = rt * 128 + wr * 64 + i * 16 + quad * 4 + reg;
                float gz = acc[i][j][reg] + bg;
                float g = 1.0f / (1.0f + expf(-gz));
                float tv = t_proj[(size_t)mm * 1024 + n];
                float rv = residual[(size_t)mm * 1024 + n];
                out[(size_t)mm * 1024 + n] = g * tv + (1.0f - g) * rv;
            }
    }
}

// ---------------------------------------------------------------------------
// Flash attention, bf16 MFMA (16x16x32) — unchanged from round 3 (verified)
// ---------------------------------------------------------------------------
#define KSTR 72

__global__ __launch_bounds__(256)
void attn_kernel(const unsigned short* __restrict__ q,
                 const unsigned short* __restrict__ k,
                 const unsigned short* __restrict__ v,
                 const float* __restrict__ bias,
                 unsigned short* __restrict__ attended) {
    int qt = blockIdx.x, h = blockIdx.y, b = blockIdx.z;
    __shared__ unsigned short Ks[64 * KSTR];
    __shared__ unsigned short Vt[64 * KSTR];
    __shared__ unsigned short Ps[64 * KSTR];
    __shared__ float af[64];
    __shared__ float lf[64];

    int tid = threadIdx.x;
    int wave = tid >> 6, lane = tid & 63;
    int quad = lane >> 4, c = lane & 15;
    int wb = wave * 16;
    size_t headbase = (((size_t)b * NHEADS + h) * SEQ) * HDIM;
    int q0 = qt * 64;

    const unsigned short* qrow = q + headbase + (size_t)(q0 + wb + c) * HDIM;
    bf16x8 aq0 = *(const bf16x8*)(qrow + quad * 8);
    bf16x8 aq1 = *(const bf16x8*)(qrow + 32 + quad * 8);

    int sr = tid >> 2, sc0 = (tid & 3) * 16;

    f32x4 oacc[4];
    #pragma unroll
    for (int t = 0; t < 4; ++t) oacc[t] = (f32x4)0.f;
    float mrow[4], lrow[4];
    #pragma unroll
    for (int r = 0; r < 4; ++r) { mrow[r] = -1e30f; lrow[r] = 0.f; }

    for (int kt = 0; kt < 8; ++kt) {
        int kv0 = kt * 64;
        __syncthreads();
        {
            const unsigned short* krow = k + headbase + (size_t)(kv0 + sr) * HDIM + sc0;
            const unsigned short* vrow = v + headbase + (size_t)(kv0 + sr) * HDIM + sc0;
            u16x8 ka = *(const u16x8*)(krow);
            u16x8 kb2 = *(const u16x8*)(krow + 8);
            u16x8 va = *(const u16x8*)(vrow);
            u16x8 vb2 = *(const u16x8*)(vrow + 8);
            *(u16x8*)&Ks[sr * KSTR + sc0] = ka;
            *(u16x8*)&Ks[sr * KSTR + sc0 + 8] = kb2;
            #pragma unroll
            for (int j = 0; j < 8; ++j) Vt[(sc0 + j) * KSTR + sr] = va[j];
            #pragma unroll
            for (int j = 0; j < 8; ++j) Vt[(sc0 + 8 + j) * KSTR + sr] = vb2[j];
        }
        __syncthreads();

        f32x4 sacc[4];
        #pragma unroll
        for (int nt = 0; nt < 4; ++nt) {
            const unsigned short* kbase = &Ks[(nt * 16 + c) * KSTR];
            bf16x8 b0 = *(const bf16x8*)(kbase + quad * 8);
            bf16x8 b1 = *(const bf16x8*)(kbase + 32 + quad * 8);
            f32x4 a = (f32x4)0.f;
            a = __builtin_amdgcn_mfma_f32_16x16x32_bf16(aq0, b0, a, 0, 0, 0);
            a = __builtin_amdgcn_mfma_f32_16x16x32_bf16(aq1, b1, a, 0, 0, 0);
            sacc[nt] = a;
        }

        const float* bbase = bias + (size_t)(q0 + wb + quad * 4) * 512 + kv0 + c;
        float tmax[4];
        #pragma unroll
        for (int r = 0; r < 4; ++r) tmax[r] = -1e30f;
        #pragma unroll
        for (int nt = 0; nt < 4; ++nt)
            #pragma unroll
            for (int r = 0; r < 4; ++r) {
                float s = sacc[nt][r] * SCALE + bbase[(size_t)r * 512 + nt * 16];
                sacc[nt][r] = s;
                tmax[r] = fmaxf(tmax[r], s);
            }
        #pragma unroll
        for (int r = 0; r < 4; ++r) {
            float t = tmax[r];
            t = fmaxf(t, __shfl_xor(t, 1));
            t = fmaxf(t, __shfl_xor(t, 2));
            t = fmaxf(t, __shfl_xor(t, 4));
            t = fmaxf(t, __shfl_xor(t, 8));
            tmax[r] = t;
        }
        float alpha[4];
        #pragma unroll
        for (int r = 0; r < 4; ++r) {
            float mnew = fmaxf(mrow[r], tmax[r]);
            alpha[r] = __expf(mrow[r] - mnew);
            mrow[r] = mnew;
        }
        float tsum[4];
        #pragma unroll
        for (int r = 0; r < 4; ++r) tsum[r] = 0.f;
        #pragma unroll
        for (int nt = 0; nt < 4; ++nt)
            #pragma unroll
            for (int r = 0; r < 4; ++r) {
                float p = __expf(sacc[nt][r] - mrow[r]);
                tsum[r] += p;
                Ps[(wb + quad * 4 + r) * KSTR + nt * 16 + c] = f2bf(p);
            }
        #pragma unroll
        for (int r = 0; r < 4; ++r) {
            float t = tsum[r];
            t += __shfl_xor(t, 1);
            t += __shfl_xor(t, 2);
            t += __shfl_xor(t, 4);
            t += __shfl_xor(t, 8);
            lrow[r] = lrow[r] * alpha[r] + t;
        }
        if (c == 0) {
            f32x4 av;
            av[0] = alpha[0]; av[1] = alpha[1]; av[2] = alpha[2]; av[3] = alpha[3];
            *(f32x4*)&af[wb + quad * 4] = av;
        }
        float myalpha = af[wb + c];
        #pragma unroll
        for (int t = 0; t < 4; ++t) oacc[t] *= myalpha;

        bf16x8 pb0 = *(const bf16x8*)&Ps[(wb + c) * KSTR + quad * 8];
        bf16x8 pb1 = *(const bf16x8*)&Ps[(wb + c) * KSTR + 32 + quad * 8];
        #pragma unroll
        for (int t = 0; t < 4; ++t) {
            const unsigned short* vbase = &Vt[(t * 16 + c) * KSTR];
            bf16x8 a0 = *(const bf16x8*)(vbase + quad * 8);
            bf16x8 a1 = *(const bf16x8*)(vbase + 32 + quad * 8);
            oacc[t] = __builtin_amdgcn_mfma_f32_16x16x32_bf16(a0, pb0, oacc[t], 0, 0, 0);
            oacc[t] = __builtin_amdgcn_mfma_f32_16x16x32_bf16(a1, pb1, oacc[t], 0, 0, 0);
        }
    }

    if (c == 0) {
        f32x4 lv;
        lv[0] = lrow[0]; lv[1] = lrow[1]; lv[2] = lrow[2]; lv[3] = lrow[3];
        *(f32x4*)&lf[wb + quad * 4] = lv;
    }
    float invl = 1.0f / lf[wb + c];
    unsigned short* drow = attended + ((size_t)b * SEQ + (q0 + wb + c)) * D_MODEL + h * HDIM;
    #pragma unroll
    for (int t = 0; t < 4; ++t) {
        ushort4 o;
        o.x = f2bf(oacc[t][0] * invl);
        o.y = f2bf(oacc[t][1] * invl);
        o.z = f2bf(oacc[t][2] * invl);
        o.w = f2bf(oacc[t][3] * invl);
        *(ushort4*)(drow + t * 16 + quad * 4) = o;
    }
}

extern "C" void kernel_launch(void* const* d_in, const int* in_sizes, int n_in,
                              void* d_out, int out_size, void* d_ws, size_t ws_size,
                              hipStream_t stream) {
    const float* dec    = (const float*)d_in[0];
    const float* enc    = (const float*)d_in[1];
    const float* Wqkv   = (const float*)d_in[2];
    const float* Wout   = (const float*)d_in[3];
    const float* b_out  = (const float*)d_in[4];
    const float* Wgate  = (const float*)d_in[5];
    const float* b_gate = (const float*)d_in[6];
    const float* gamma  = (const float*)d_in[7];
    const float* beta   = (const float*)d_in[8];
    float* out = (float*)d_out;

    char* ws = (char*)d_ws;
    const size_t MB = 1024 * 1024;
    // Workspace overlay plan (peak 47 MB):
    //   [0,8)   q_ln (dead after qkv_gemm)        -> att (written by attn)
    //   [8,16)  kv_ln (dead after qkv_gemm)  \
    //   [16,24) qb (dead after attn)          }-> t_proj fp32 [8,24)
    //   [24,32) kb (dead after attn)         -> t_bf
    //   [32,40) vb (dead after attn)         -> Wout_bf [32,34) + Wgate_bf [34,36)
    //   [40,46) Wqkv_bf
    //   [46,47) bias
    unsigned short* q_ln    = (unsigned short*)(ws + 0 * MB);
    unsigned short* kv_ln   = (unsigned short*)(ws + 8 * MB);
    unsigned short* qb      = (unsigned short*)(ws + 16 * MB);
    unsigned short* kb      = (unsigned short*)(ws + 24 * MB);
    unsigned short* vb      = (unsigned short*)(ws + 32 * MB);
    unsigned short* Wqkv_bf = (unsigned short*)(ws + 40 * MB);
    float*          bias    = (float*)(ws + 46 * MB);
    unsigned short* att     = (unsigned short*)(ws + 0 * MB);
    float*          t_proj  = (float*)(ws + 8 * MB);
    unsigned short* t_bf    = (unsigned short*)(ws + 24 * MB);
    unsigned short* Wout_bf = (unsigned short*)(ws + 32 * MB);
    unsigned short* Wgate_bf= (unsigned short*)(ws + 34 * MB);

    bias_kernel<<<1024, 256, 0, stream>>>(bias);
    ln_kernel<<<8192, 256, 0, stream>>>(dec, enc, gamma, beta, q_ln, kv_ln);
    f32_to_bf16<<<3072, 256, 0, stream>>>(Wqkv, Wqkv_bf, 3072 * 1024 / 4);
    qkv_gemm_mfma<<<dim3(24, 32), 256, 0, stream>>>(q_ln, kv_ln, Wqkv_bf, qb, kb, vb);
    attn_kernel<<<dim3(8, 16, 8), 256, 0, stream>>>(qb, kb, vb, bias, att);
    f32_to_bf16<<<1024, 256, 0, stream>>>(Wout, Wout_bf, 1024 * 1024 / 4);
    f32_to_bf16<<<1024, 256, 0, stream>>>(Wgate, Wgate_bf, 1024 * 1024 / 4);
    out_gemm1_mfma<<<dim3(8, 32), 256, 0, stream>>>(att, Wout_bf, b_out, t_proj, t_bf);
    out_gemm2_mfma<<<dim3(8, 32), 256, 0, stream>>>(t_bf, Wgate_bf, b_gate, t_proj, dec, out);
}